// Round 14
// baseline (50.334 us; speedup 1.0000x reference)
//
#include <hip/hip_runtime.h>

#ifndef __has_builtin
#define __has_builtin(x) 0
#endif

#if __has_builtin(__builtin_amdgcn_exp2f)
#define EXP2F(x) __builtin_amdgcn_exp2f(x)
#else
#define EXP2F(x) exp2f(x)
#endif
#if __has_builtin(__builtin_amdgcn_rcpf)
#define RCPF(x) __builtin_amdgcn_rcpf(x)
#else
#define RCPF(x) (1.0f / (x))
#endif

static constexpr int NB = 4, NQ = 512, NK = 512, DD = 512, HH = 128, DV = 512;
static constexpr float MASKV = -1e6f;
static constexpr float C2LOG2E = 2.885390081777926814f;  // 2*log2(e)

typedef __attribute__((ext_vector_type(8))) short bf16x8;
typedef __attribute__((ext_vector_type(4))) float f32x4;

__device__ __forceinline__ unsigned short f2bf(float x) {  // RNE f32->bf16
  unsigned int u = __float_as_uint(x);
  u += 0x7FFFu + ((u >> 16) & 1u);
  return (unsigned short)(u >> 16);
}
__device__ __forceinline__ float bf2f(unsigned short h) {
  return __uint_as_float(((unsigned int)h) << 16);
}
// split x = hi + lo (lo exact residual, then rounded): |x-hi-lo| <= 2^-18|x|
__device__ __forceinline__ void split2(float x, unsigned short& hi, unsigned short& lo) {
  hi = f2bf(x);
  lo = f2bf(x - bf2f(hi));
}

// ---------------------------------------------------------------------------
// K1: 512 blocks.  (R12-proven, FROZEN)
//  bid 0..255  : projection via split-bf16 MFMA, tile 16 rows x 128 h, full K.
//  bid 256..511: V transpose -> Vt[b][v][k] bf16.
// ---------------------------------------------------------------------------
__global__ __launch_bounds__(256) void proj_mfma_vt_kernel(
    const float* __restrict__ queries, const float* __restrict__ keys,
    const float* __restrict__ Wq, const float* __restrict__ Wk,
    const float* __restrict__ values, const int* __restrict__ valid_lens,
    float* __restrict__ eq, float* __restrict__ ekT4,
    unsigned short* __restrict__ Vt) {
  __shared__ __align__(16) unsigned short smem_us[20736];  // 41.5 KB
  const int bid = blockIdx.x;
  const int t = threadIdx.x;

  if (bid < 256) {
    const int row0 = bid << 4;
    const bool isK = row0 >= 2048;
    int b = 0, kloc = 0;
    const float* inb;
    const float* W;
    if (isK) {
      const int local = row0 - 2048;
      b = local >> 9;
      kloc = local & 511;
      if (kloc >= valid_lens[b]) return;  // fully-masked tile, never read
      inb = keys + (size_t)local * DD;
      W = Wk;
    } else {
      inb = queries + (size_t)row0 * DD;
      W = Wq;
    }

    unsigned short* Ah = smem_us;          // [16][72]
    unsigned short* Al = smem_us + 1152;   // [16][72]
    unsigned short* Wh = smem_us + 2304;   // [128][72] ([h][k])
    unsigned short* Wl = smem_us + 11520;  // [128][72]

    const int w = t >> 6, l = t & 63;
    const int lm = l & 15;
    const int lk8 = (l >> 4) << 3;

    const f32x4 z = {0.f, 0.f, 0.f, 0.f};
    f32x4 acc[2] = {z, z};  // col tiles h = 32w+0..15, 32w+16..31

    const int ar = t >> 4, ac4 = (t & 15) << 2;        // A staging: row, k4
    const int wh = t & 127, wkg = (t >> 7) << 5;       // W staging: h, k-group

    for (int kt = 0; kt < 8; ++kt) {
      const int k0 = kt << 6;
      {  // stage A: 16 rows x 64 k, split hi/lo, pack k-pairs into u32
        const float4 v = *reinterpret_cast<const float4*>(inb + (size_t)ar * DD + k0 + ac4);
        unsigned short h0, h1, h2, h3, l0, l1, l2, l3;
        split2(v.x, h0, l0); split2(v.y, h1, l1);
        split2(v.z, h2, l2); split2(v.w, h3, l3);
        uint2 ph = make_uint2((unsigned int)h0 | ((unsigned int)h1 << 16),
                              (unsigned int)h2 | ((unsigned int)h3 << 16));
        uint2 pl = make_uint2((unsigned int)l0 | ((unsigned int)l1 << 16),
                              (unsigned int)l2 | ((unsigned int)l3 << 16));
        *reinterpret_cast<uint2*>(Ah + ar * 72 + ac4) = ph;
        *reinterpret_cast<uint2*>(Al + ar * 72 + ac4) = pl;
      }
      {  // stage W transposed: [h][k], 32 k per thread (coalesced b32 loads)
        unsigned int hw[16], lw[16];
#pragma unroll
        for (int i = 0; i < 16; ++i) {
          const float w0 = W[(size_t)(k0 + wkg + 2 * i) * HH + wh];
          const float w1 = W[(size_t)(k0 + wkg + 2 * i + 1) * HH + wh];
          unsigned short a0, a1, b0, b1;
          split2(w0, a0, b0); split2(w1, a1, b1);
          hw[i] = (unsigned int)a0 | ((unsigned int)a1 << 16);
          lw[i] = (unsigned int)b0 | ((unsigned int)b1 << 16);
        }
        unsigned int* dh = reinterpret_cast<unsigned int*>(Wh + wh * 72 + wkg);
        unsigned int* dl = reinterpret_cast<unsigned int*>(Wl + wh * 72 + wkg);
#pragma unroll
        for (int i = 0; i < 4; ++i) {
          *reinterpret_cast<uint4*>(dh + 4 * i) =
              make_uint4(hw[4 * i], hw[4 * i + 1], hw[4 * i + 2], hw[4 * i + 3]);
          *reinterpret_cast<uint4*>(dl + 4 * i) =
              make_uint4(lw[4 * i], lw[4 * i + 1], lw[4 * i + 2], lw[4 * i + 3]);
        }
      }
      __syncthreads();

#pragma unroll
      for (int kh = 0; kh < 2; ++kh) {  // k halves 0..31 / 32..63
        const int ko = lk8 + (kh << 5);
        const bf16x8 ah = *reinterpret_cast<const bf16x8*>(Ah + lm * 72 + ko);
        const bf16x8 al = *reinterpret_cast<const bf16x8*>(Al + lm * 72 + ko);
#pragma unroll
        for (int c = 0; c < 2; ++c) {
          const int hrow = (w << 5) + (c << 4) + lm;
          const bf16x8 bh = *reinterpret_cast<const bf16x8*>(Wh + hrow * 72 + ko);
          const bf16x8 bl = *reinterpret_cast<const bf16x8*>(Wl + hrow * 72 + ko);
          acc[c] = __builtin_amdgcn_mfma_f32_16x16x32_bf16(ah, bh, acc[c], 0, 0, 0);
          acc[c] = __builtin_amdgcn_mfma_f32_16x16x32_bf16(al, bh, acc[c], 0, 0, 0);
          acc[c] = __builtin_amdgcn_mfma_f32_16x16x32_bf16(ah, bl, acc[c], 0, 0, 0);
        }
      }
      __syncthreads();
    }

    // epilogue: D mapping col=lane&15, row=(lane>>4)*4+j  [m89-verified]
    const int rb = (l >> 4) << 2;
    if (!isK) {
#pragma unroll
      for (int c = 0; c < 2; ++c) {
        const int h = (w << 5) + (c << 4) + lm;
#pragma unroll
        for (int j = 0; j < 4; ++j)
          eq[(size_t)(row0 + rb + j) * HH + h] = EXP2F(acc[c][j] * C2LOG2E);
      }
    } else {
      float* tile = reinterpret_cast<float*>(smem_us);  // [16][132] f32
#pragma unroll
      for (int c = 0; c < 2; ++c) {
        const int h = (w << 5) + (c << 4) + lm;
#pragma unroll
        for (int j = 0; j < 4; ++j)
          tile[(rb + j) * 132 + h] = EXP2F(acc[c][j] * C2LOG2E);
      }
      __syncthreads();
#pragma unroll
      for (int i = 0; i < 2; ++i) {
        const int idx = t + (i << 8);
        const int k = idx & 15, h4 = idx >> 4;  // h4 0..31
        const float4 v = *reinterpret_cast<const float4*>(tile + k * 132 + (h4 << 2));
        *reinterpret_cast<float4*>(
            ekT4 + ((((size_t)b * 32 + h4) << 9) + kloc + k) * 4) = v;
      }
    }
  } else {
    // V transpose (R10-proven)
    unsigned short (*tl)[72] = reinterpret_cast<unsigned short (*)[72]>(smem_us);
    const int vb = bid - 256;
    const int b = vb >> 6;
    const int tile = vb & 63;
    const int k0 = (tile >> 3) << 6;
    const int v0 = (tile & 7) << 6;
    const int kr = t >> 4, c4 = (t & 15) << 2;
#pragma unroll
    for (int pp = 0; pp < 4; ++pp) {
      const int k = kr + (pp << 4);
      const float4 v = *reinterpret_cast<const float4*>(
          values + ((size_t)(b * NK + k0 + k)) * DV + v0 + c4);
      tl[k][c4 + 0] = f2bf(v.x); tl[k][c4 + 1] = f2bf(v.y);
      tl[k][c4 + 2] = f2bf(v.z); tl[k][c4 + 3] = f2bf(v.w);
    }
    __syncthreads();
    const int vr = t >> 2, seg = t & 3;
    unsigned int pk[8];
#pragma unroll
    for (int i = 0; i < 8; ++i) {
      const int kc = (seg << 4) + (i << 1);
      pk[i] = (unsigned int)tl[kc][vr] | ((unsigned int)tl[kc + 1][vr] << 16);
    }
    unsigned short* dst = Vt + ((size_t)(b * NK + v0 + vr)) * NK + k0 + (seg << 4);
    *reinterpret_cast<uint4*>(dst) = make_uint4(pk[0], pk[1], pk[2], pk[3]);
    *reinterpret_cast<uint4*>(dst + 8) = make_uint4(pk[4], pk[5], pk[6], pk[7]);
  }
}

// ---------------------------------------------------------------------------
// K2: scores + masked softmax. CHANGE (R14): 1024 blocks x 512 thr, q-tile 2,
// b = bid & 3 -> every CU's 4 resident blocks cover ALL FOUR batches, making
// per-CU work ~Sigma(vl)/4 independent of the valid_lens draw. Inner loop =
// R13's paired-rcp form, h unsplit (32 iters). Output attnQ[b][q][k] bf16.
// ---------------------------------------------------------------------------
__global__ __launch_bounds__(512) void scores_softmax_kernel(
    const float* __restrict__ eq, const float* __restrict__ ekT4,
    const float* __restrict__ Wv, const int* __restrict__ valid_lens,
    unsigned short* __restrict__ attnQ) {
  const int b = blockIdx.x & 3;
  const int q0 = (blockIdx.x >> 2) << 1;
  const int t = threadIdx.x;

  __shared__ __align__(16) float qs[2][HH];
  __shared__ __align__(16) float wv[HH];
  __shared__ __align__(16) float scp[2][NK];  // 4 KB

  if (t < 256) {
    qs[t >> 7][t & 127] = eq[((size_t)(b * NQ + q0 + (t >> 7))) * HH + (t & 127)];
  } else if (t < 384) {
    wv[t - 256] = Wv[t - 256];
  }
  __syncthreads();

  const int vl = valid_lens[b];
  float s0 = 0.f, s1 = 0.f;

  if (t < vl) {
    const float* ekb4 = ekT4 + ((((size_t)b * 32) << 9) + t) * 4;  // [b][h4][k][4]
#pragma unroll 8
    for (int i = 0; i < 32; ++i) {
      const float4 e4 = *reinterpret_cast<const float4*>(ekb4 + ((size_t)i << 11));
      const int h = i << 2;
      const float4 w4 = *reinterpret_cast<const float4*>(&wv[h]);
      const float4 qa = *reinterpret_cast<const float4*>(&qs[0][h]);
      const float4 qb = *reinterpret_cast<const float4*>(&qs[1][h]);
      float u, v, num, r;
      // q-row 0: pairs (x,y), (z,w)
      u = fmaf(qa.x, e4.x, 1.f); v = fmaf(qa.y, e4.y, 1.f);
      num = fmaf(w4.x, v, w4.y * u); r = RCPF(u * v); s0 = fmaf(num, r, s0);
      u = fmaf(qa.z, e4.z, 1.f); v = fmaf(qa.w, e4.w, 1.f);
      num = fmaf(w4.z, v, w4.w * u); r = RCPF(u * v); s0 = fmaf(num, r, s0);
      // q-row 1
      u = fmaf(qb.x, e4.x, 1.f); v = fmaf(qb.y, e4.y, 1.f);
      num = fmaf(w4.x, v, w4.y * u); r = RCPF(u * v); s1 = fmaf(num, r, s1);
      u = fmaf(qb.z, e4.z, 1.f); v = fmaf(qb.w, e4.w, 1.f);
      num = fmaf(w4.z, v, w4.w * u); r = RCPF(u * v); s1 = fmaf(num, r, s1);
    }
  }
  const bool act = (t < vl);
  scp[0][t] = act ? (-2.f * s0) : MASKV;
  scp[1][t] = act ? (-2.f * s1) : MASKV;
  __syncthreads();

  // softmax: waves 0..1 handle q-rows 0..1 over all 512 keys
  if (t < 128) {
    const int w = t >> 6, l = t & 63;
    float v[8];
#pragma unroll
    for (int j = 0; j < 8; ++j) v[j] = scp[w][l + (j << 6)];
    float m = v[0];
#pragma unroll
    for (int j = 1; j < 8; ++j) m = fmaxf(m, v[j]);
#pragma unroll
    for (int off = 32; off > 0; off >>= 1) m = fmaxf(m, __shfl_xor(m, off, 64));
    float p[8], sum = 0.f;
#pragma unroll
    for (int j = 0; j < 8; ++j) {
      p[j] = __expf(v[j] - m);  // masked: underflows to exactly 0
      sum += p[j];
    }
#pragma unroll
    for (int off = 32; off > 0; off >>= 1) sum += __shfl_xor(sum, off, 64);
    const float inv = RCPF(sum);
#pragma unroll
    for (int j = 0; j < 8; ++j) scp[w][l + (j << 6)] = p[j] * inv;
  }
  __syncthreads();

  attnQ[((size_t)(b * NQ + q0 + 0)) * NK + t] = f2bf(scp[0][t]);
  attnQ[((size_t)(b * NQ + q0 + 1)) * NK + t] = f2bf(scp[1][t]);
}

// ---------------------------------------------------------------------------
// K3: PV via MFMA bf16. CHANGE (R14): tile 64q x 32v -> 512 blocks, b=bid&3
// (each CU: 2 blocks, 2 batches -> makespan ~ (vlA+vlB)/2, was max_b vl).
// Wave = 16q x 32v: 1 A-frag x 2 B-frags, same m89-verified geometry.
// Row stride 40 ushorts (bank-checked: write banks 5t mod 32 distinct;
// read stride 80 B -> 2-way aliasing = free per m136).
// ---------------------------------------------------------------------------
__global__ __launch_bounds__(256) void pv_mfma_kernel(
    const unsigned short* __restrict__ attnQ, const unsigned short* __restrict__ Vt,
    const int* __restrict__ valid_lens, float* __restrict__ out) {
  const int bid = blockIdx.x;
  const int b = bid & 3;
  const int tile = bid >> 2;        // 0..127
  const int q0 = (tile >> 4) << 6;  // 8 q-tiles of 64
  const int v0 = (tile & 15) << 5;  // 16 v-tiles of 32

  __shared__ __align__(16) unsigned short Als[64 * 40];  // [q][k], 5 KB
  __shared__ __align__(16) unsigned short Bls[32 * 40];  // [v][k], 2.5 KB

  const int t = threadIdx.x;
  const int w = t >> 6, l = t & 63;
  const int lm = l & 15;
  const int lk = (l >> 4) << 3;

  const f32x4 z = {0.f, 0.f, 0.f, 0.f};
  f32x4 acc[2] = {z, z};

  const int vl = valid_lens[b];
  const int nkt = (vl + 31) >> 5;

  const int sq = t >> 2, seg = t & 3;
  const unsigned short* arow = attnQ + ((size_t)(b * NQ + q0 + sq)) * NK;
  unsigned short* alds = &Als[sq * 40 + (seg << 3)];
  const unsigned short* brow = Vt + ((size_t)(b * NK + v0 + (t >> 2))) * NK;
  unsigned short* blds = &Bls[(t >> 2) * 40 + (seg << 3)];

  for (int kt = 0; kt < nkt; ++kt) {
    const int k0 = kt << 5;
    *reinterpret_cast<bf16x8*>(alds) =
        *reinterpret_cast<const bf16x8*>(arow + k0 + (seg << 3));
    if (t < 128)
      *reinterpret_cast<bf16x8*>(blds) =
          *reinterpret_cast<const bf16x8*>(brow + k0 + (seg << 3));
    __syncthreads();

    const bf16x8 af = *reinterpret_cast<const bf16x8*>(
        &Als[((w << 4) + lm) * 40 + lk]);
#pragma unroll
    for (int nv = 0; nv < 2; ++nv) {
      const bf16x8 bfr = *reinterpret_cast<const bf16x8*>(
          &Bls[((nv << 4) + lm) * 40 + lk]);
      acc[nv] = __builtin_amdgcn_mfma_f32_16x16x32_bf16(af, bfr, acc[nv], 0, 0, 0);
    }
    __syncthreads();
  }

  // epilogue: D lane mapping col=lane&15, row=(lane>>4)*4+j  [m89-verified]
  const int rbase = (l >> 4) << 2;
#pragma unroll
  for (int nv = 0; nv < 2; ++nv) {
    const int qg = q0 + (w << 4) + rbase;
    const int vg = v0 + (nv << 4) + lm;
#pragma unroll
    for (int j = 0; j < 4; ++j)
      out[((size_t)(b * NQ + qg + j)) * DV + vg] = acc[nv][j];
  }
}

extern "C" void kernel_launch(void* const* d_in, const int* in_sizes, int n_in,
                              void* d_out, int out_size, void* d_ws, size_t ws_size,
                              hipStream_t stream) {
  (void)in_sizes; (void)n_in; (void)out_size; (void)ws_size;
  const float* queries = (const float*)d_in[0];
  const float* keys    = (const float*)d_in[1];
  const float* values  = (const float*)d_in[2];
  const float* Wq      = (const float*)d_in[3];
  const float* Wk      = (const float*)d_in[4];
  const float* Wv      = (const float*)d_in[5];
  const int*   vlens   = (const int*)d_in[6];
  float* out = (float*)d_out;
  float* ws = (float*)d_ws;

  // ws floats (NON-OVERLAPPING):
  //   eq    [0,        262144)
  //   ekT4  [262144,   524288)
  //   attnQ [524288,  1048576)  (1,048,576 ushort)
  //   Vt    [1048576, 1572864)  (1,048,576 ushort)
  float* eq   = ws;
  float* ekT4 = ws + 262144;
  unsigned short* attnQ = (unsigned short*)(ws + 524288);
  unsigned short* Vt    = (unsigned short*)(ws + 1048576);

  proj_mfma_vt_kernel<<<512, 256, 0, stream>>>(queries, keys, Wq, Wk, values,
                                               vlens, eq, ekT4, Vt);
  scores_softmax_kernel<<<1024, 512, 0, stream>>>(eq, ekT4, Wv, vlens, attnQ);
  pv_mfma_kernel<<<512, 256, 0, stream>>>(attnQ, Vt, vlens, out);
}

// Round 15
// 44.874 us; speedup vs baseline: 1.1217x; 1.1217x over previous
//
#include <hip/hip_runtime.h>

#ifndef __has_builtin
#define __has_builtin(x) 0
#endif

#if __has_builtin(__builtin_amdgcn_exp2f)
#define EXP2F(x) __builtin_amdgcn_exp2f(x)
#else
#define EXP2F(x) exp2f(x)
#endif
#if __has_builtin(__builtin_amdgcn_rcpf)
#define RCPF(x) __builtin_amdgcn_rcpf(x)
#else
#define RCPF(x) (1.0f / (x))
#endif

static constexpr int NB = 4, NQ = 512, NK = 512, DD = 512, HH = 128, DV = 512;
static constexpr float MASKV = -1e6f;
static constexpr float C2LOG2E = 2.885390081777926814f;  // 2*log2(e)

typedef __attribute__((ext_vector_type(8))) short bf16x8;
typedef __attribute__((ext_vector_type(4))) float f32x4;

__device__ __forceinline__ unsigned short f2bf(float x) {  // RNE f32->bf16
  unsigned int u = __float_as_uint(x);
  u += 0x7FFFu + ((u >> 16) & 1u);
  return (unsigned short)(u >> 16);
}
__device__ __forceinline__ float bf2f(unsigned short h) {
  return __uint_as_float(((unsigned int)h) << 16);
}
// split x = hi + lo (lo exact residual, then rounded): |x-hi-lo| <= 2^-18|x|
__device__ __forceinline__ void split2(float x, unsigned short& hi, unsigned short& lo) {
  hi = f2bf(x);
  lo = f2bf(x - bf2f(hi));
}

// ---------------------------------------------------------------------------
// K1: 512 blocks.  (R12-proven, FROZEN)
//  bid 0..255  : projection via split-bf16 MFMA, tile 16 rows x 128 h, full K.
//  bid 256..511: V transpose -> Vt[b][v][k] bf16.
// ---------------------------------------------------------------------------
__global__ __launch_bounds__(256) void proj_mfma_vt_kernel(
    const float* __restrict__ queries, const float* __restrict__ keys,
    const float* __restrict__ Wq, const float* __restrict__ Wk,
    const float* __restrict__ values, const int* __restrict__ valid_lens,
    float* __restrict__ eq, float* __restrict__ ekT4,
    unsigned short* __restrict__ Vt) {
  __shared__ __align__(16) unsigned short smem_us[20736];  // 41.5 KB
  const int bid = blockIdx.x;
  const int t = threadIdx.x;

  if (bid < 256) {
    const int row0 = bid << 4;
    const bool isK = row0 >= 2048;
    int b = 0, kloc = 0;
    const float* inb;
    const float* W;
    if (isK) {
      const int local = row0 - 2048;
      b = local >> 9;
      kloc = local & 511;
      if (kloc >= valid_lens[b]) return;  // fully-masked tile, never read
      inb = keys + (size_t)local * DD;
      W = Wk;
    } else {
      inb = queries + (size_t)row0 * DD;
      W = Wq;
    }

    unsigned short* Ah = smem_us;          // [16][72]
    unsigned short* Al = smem_us + 1152;   // [16][72]
    unsigned short* Wh = smem_us + 2304;   // [128][72] ([h][k])
    unsigned short* Wl = smem_us + 11520;  // [128][72]

    const int w = t >> 6, l = t & 63;
    const int lm = l & 15;
    const int lk8 = (l >> 4) << 3;

    const f32x4 z = {0.f, 0.f, 0.f, 0.f};
    f32x4 acc[2] = {z, z};  // col tiles h = 32w+0..15, 32w+16..31

    const int ar = t >> 4, ac4 = (t & 15) << 2;        // A staging: row, k4
    const int wh = t & 127, wkg = (t >> 7) << 5;       // W staging: h, k-group

    for (int kt = 0; kt < 8; ++kt) {
      const int k0 = kt << 6;
      {  // stage A: 16 rows x 64 k, split hi/lo, pack k-pairs into u32
        const float4 v = *reinterpret_cast<const float4*>(inb + (size_t)ar * DD + k0 + ac4);
        unsigned short h0, h1, h2, h3, l0, l1, l2, l3;
        split2(v.x, h0, l0); split2(v.y, h1, l1);
        split2(v.z, h2, l2); split2(v.w, h3, l3);
        uint2 ph = make_uint2((unsigned int)h0 | ((unsigned int)h1 << 16),
                              (unsigned int)h2 | ((unsigned int)h3 << 16));
        uint2 pl = make_uint2((unsigned int)l0 | ((unsigned int)l1 << 16),
                              (unsigned int)l2 | ((unsigned int)l3 << 16));
        *reinterpret_cast<uint2*>(Ah + ar * 72 + ac4) = ph;
        *reinterpret_cast<uint2*>(Al + ar * 72 + ac4) = pl;
      }
      {  // stage W transposed: [h][k], 32 k per thread (coalesced b32 loads)
        unsigned int hw[16], lw[16];
#pragma unroll
        for (int i = 0; i < 16; ++i) {
          const float w0 = W[(size_t)(k0 + wkg + 2 * i) * HH + wh];
          const float w1 = W[(size_t)(k0 + wkg + 2 * i + 1) * HH + wh];
          unsigned short a0, a1, b0, b1;
          split2(w0, a0, b0); split2(w1, a1, b1);
          hw[i] = (unsigned int)a0 | ((unsigned int)a1 << 16);
          lw[i] = (unsigned int)b0 | ((unsigned int)b1 << 16);
        }
        unsigned int* dh = reinterpret_cast<unsigned int*>(Wh + wh * 72 + wkg);
        unsigned int* dl = reinterpret_cast<unsigned int*>(Wl + wh * 72 + wkg);
#pragma unroll
        for (int i = 0; i < 4; ++i) {
          *reinterpret_cast<uint4*>(dh + 4 * i) =
              make_uint4(hw[4 * i], hw[4 * i + 1], hw[4 * i + 2], hw[4 * i + 3]);
          *reinterpret_cast<uint4*>(dl + 4 * i) =
              make_uint4(lw[4 * i], lw[4 * i + 1], lw[4 * i + 2], lw[4 * i + 3]);
        }
      }
      __syncthreads();

#pragma unroll
      for (int kh = 0; kh < 2; ++kh) {  // k halves 0..31 / 32..63
        const int ko = lk8 + (kh << 5);
        const bf16x8 ah = *reinterpret_cast<const bf16x8*>(Ah + lm * 72 + ko);
        const bf16x8 al = *reinterpret_cast<const bf16x8*>(Al + lm * 72 + ko);
#pragma unroll
        for (int c = 0; c < 2; ++c) {
          const int hrow = (w << 5) + (c << 4) + lm;
          const bf16x8 bh = *reinterpret_cast<const bf16x8*>(Wh + hrow * 72 + ko);
          const bf16x8 bl = *reinterpret_cast<const bf16x8*>(Wl + hrow * 72 + ko);
          acc[c] = __builtin_amdgcn_mfma_f32_16x16x32_bf16(ah, bh, acc[c], 0, 0, 0);
          acc[c] = __builtin_amdgcn_mfma_f32_16x16x32_bf16(al, bh, acc[c], 0, 0, 0);
          acc[c] = __builtin_amdgcn_mfma_f32_16x16x32_bf16(ah, bl, acc[c], 0, 0, 0);
        }
      }
      __syncthreads();
    }

    // epilogue: D mapping col=lane&15, row=(lane>>4)*4+j  [m89-verified]
    const int rb = (l >> 4) << 2;
    if (!isK) {
#pragma unroll
      for (int c = 0; c < 2; ++c) {
        const int h = (w << 5) + (c << 4) + lm;
#pragma unroll
        for (int j = 0; j < 4; ++j)
          eq[(size_t)(row0 + rb + j) * HH + h] = EXP2F(acc[c][j] * C2LOG2E);
      }
    } else {
      float* tile = reinterpret_cast<float*>(smem_us);  // [16][132] f32
#pragma unroll
      for (int c = 0; c < 2; ++c) {
        const int h = (w << 5) + (c << 4) + lm;
#pragma unroll
        for (int j = 0; j < 4; ++j)
          tile[(rb + j) * 132 + h] = EXP2F(acc[c][j] * C2LOG2E);
      }
      __syncthreads();
#pragma unroll
      for (int i = 0; i < 2; ++i) {
        const int idx = t + (i << 8);
        const int k = idx & 15, h4 = idx >> 4;  // h4 0..31
        const float4 v = *reinterpret_cast<const float4*>(tile + k * 132 + (h4 << 2));
        *reinterpret_cast<float4*>(
            ekT4 + ((((size_t)b * 32 + h4) << 9) + kloc + k) * 4) = v;
      }
    }
  } else {
    // V transpose (R10-proven)
    unsigned short (*tl)[72] = reinterpret_cast<unsigned short (*)[72]>(smem_us);
    const int vb = bid - 256;
    const int b = vb >> 6;
    const int tile = vb & 63;
    const int k0 = (tile >> 3) << 6;
    const int v0 = (tile & 7) << 6;
    const int kr = t >> 4, c4 = (t & 15) << 2;
#pragma unroll
    for (int pp = 0; pp < 4; ++pp) {
      const int k = kr + (pp << 4);
      const float4 v = *reinterpret_cast<const float4*>(
          values + ((size_t)(b * NK + k0 + k)) * DV + v0 + c4);
      tl[k][c4 + 0] = f2bf(v.x); tl[k][c4 + 1] = f2bf(v.y);
      tl[k][c4 + 2] = f2bf(v.z); tl[k][c4 + 3] = f2bf(v.w);
    }
    __syncthreads();
    const int vr = t >> 2, seg = t & 3;
    unsigned int pk[8];
#pragma unroll
    for (int i = 0; i < 8; ++i) {
      const int kc = (seg << 4) + (i << 1);
      pk[i] = (unsigned int)tl[kc][vr] | ((unsigned int)tl[kc + 1][vr] << 16);
    }
    unsigned short* dst = Vt + ((size_t)(b * NK + v0 + vr)) * NK + k0 + (seg << 4);
    *reinterpret_cast<uint4*>(dst) = make_uint4(pk[0], pk[1], pk[2], pk[3]);
    *reinterpret_cast<uint4*>(dst + 8) = make_uint4(pk[4], pk[5], pk[6], pk[7]);
  }
}

// ---------------------------------------------------------------------------
// K2: scores + masked softmax (R13-proven, RESTORED). 512 blocks x 1024 thr,
// q-tile 4, h-split x2; b = bid>>7 so each CU's 2 blocks pair batches
// {0,2}/{1,3}. Paired-rcp inner loop. Output attnQ[b][q][k] bf16.
// ---------------------------------------------------------------------------
__global__ __launch_bounds__(1024) void scores_softmax_kernel(
    const float* __restrict__ eq, const float* __restrict__ ekT4,
    const float* __restrict__ Wv, const int* __restrict__ valid_lens,
    unsigned short* __restrict__ attnQ) {
  const int b = blockIdx.x >> 7;
  const int q0 = (blockIdx.x & 127) << 2;
  const int t = threadIdx.x;
  const int kk = t & 511, hh = t >> 9;

  __shared__ __align__(16) float qs[4][HH];
  __shared__ __align__(16) float wv[HH];
  __shared__ __align__(16) float scp[2][4][NK];  // 16 KB partials

  if (t < 512) {
    qs[t >> 7][t & 127] = eq[((size_t)(b * NQ + q0 + (t >> 7))) * HH + (t & 127)];
  } else if (t < 640) {
    wv[t - 512] = Wv[t - 512];
  }
  __syncthreads();

  const int vl = valid_lens[b];
  float s0 = 0.f, s1 = 0.f, s2 = 0.f, s3 = 0.f;

  if (kk < vl) {
    const float* ekb4 = ekT4 + (((size_t)(b * 32 + hh * 16) << 9) + kk) * 4;
#pragma unroll 8
    for (int i = 0; i < 16; ++i) {
      const float4 e4 = *reinterpret_cast<const float4*>(ekb4 + ((size_t)i << 11));
      const int h = (hh * 16 + i) << 2;
      const float4 w4 = *reinterpret_cast<const float4*>(&wv[h]);
      const float4 qa = *reinterpret_cast<const float4*>(&qs[0][h]);
      const float4 qb = *reinterpret_cast<const float4*>(&qs[1][h]);
      const float4 qc = *reinterpret_cast<const float4*>(&qs[2][h]);
      const float4 qd = *reinterpret_cast<const float4*>(&qs[3][h]);
      float u, v, num, r;
      // q-row 0: pairs (x,y), (z,w)
      u = fmaf(qa.x, e4.x, 1.f); v = fmaf(qa.y, e4.y, 1.f);
      num = fmaf(w4.x, v, w4.y * u); r = RCPF(u * v); s0 = fmaf(num, r, s0);
      u = fmaf(qa.z, e4.z, 1.f); v = fmaf(qa.w, e4.w, 1.f);
      num = fmaf(w4.z, v, w4.w * u); r = RCPF(u * v); s0 = fmaf(num, r, s0);
      // q-row 1
      u = fmaf(qb.x, e4.x, 1.f); v = fmaf(qb.y, e4.y, 1.f);
      num = fmaf(w4.x, v, w4.y * u); r = RCPF(u * v); s1 = fmaf(num, r, s1);
      u = fmaf(qb.z, e4.z, 1.f); v = fmaf(qb.w, e4.w, 1.f);
      num = fmaf(w4.z, v, w4.w * u); r = RCPF(u * v); s1 = fmaf(num, r, s1);
      // q-row 2
      u = fmaf(qc.x, e4.x, 1.f); v = fmaf(qc.y, e4.y, 1.f);
      num = fmaf(w4.x, v, w4.y * u); r = RCPF(u * v); s2 = fmaf(num, r, s2);
      u = fmaf(qc.z, e4.z, 1.f); v = fmaf(qc.w, e4.w, 1.f);
      num = fmaf(w4.z, v, w4.w * u); r = RCPF(u * v); s2 = fmaf(num, r, s2);
      // q-row 3
      u = fmaf(qd.x, e4.x, 1.f); v = fmaf(qd.y, e4.y, 1.f);
      num = fmaf(w4.x, v, w4.y * u); r = RCPF(u * v); s3 = fmaf(num, r, s3);
      u = fmaf(qd.z, e4.z, 1.f); v = fmaf(qd.w, e4.w, 1.f);
      num = fmaf(w4.z, v, w4.w * u); r = RCPF(u * v); s3 = fmaf(num, r, s3);
    }
  }
  scp[hh][0][kk] = s0;
  scp[hh][1][kk] = s1;
  scp[hh][2][kk] = s2;
  scp[hh][3][kk] = s3;
  __syncthreads();

  if (t < 256) {
    const int w = t >> 6, l = t & 63;
    float v[8];
#pragma unroll
    for (int j = 0; j < 8; ++j) {
      const int k = l + (j << 6);
      const float sv = scp[0][w][k] + scp[1][w][k];
      v[j] = (k < vl) ? (-2.f * sv) : MASKV;
    }
    float m = v[0];
#pragma unroll
    for (int j = 1; j < 8; ++j) m = fmaxf(m, v[j]);
#pragma unroll
    for (int off = 32; off > 0; off >>= 1) m = fmaxf(m, __shfl_xor(m, off, 64));
    float p[8], sum = 0.f;
#pragma unroll
    for (int j = 0; j < 8; ++j) {
      p[j] = __expf(v[j] - m);  // masked: underflows to exactly 0
      sum += p[j];
    }
#pragma unroll
    for (int off = 32; off > 0; off >>= 1) sum += __shfl_xor(sum, off, 64);
    const float inv = RCPF(sum);
#pragma unroll
    for (int j = 0; j < 8; ++j) scp[0][w][l + (j << 6)] = p[j] * inv;
  }
  __syncthreads();

  if (t < 512) {
#pragma unroll
    for (int j = 0; j < 4; ++j)
      attnQ[((size_t)(b * NQ + q0 + j)) * NK + t] = f2bf(scp[0][j][t]);
  }
}

// ---------------------------------------------------------------------------
// K3: PV via MFMA bf16, 64q x 32v, 512 blocks. CHANGE (R15): FIXED batch
// pairing: b = (bid&1) | ((bid>>8)<<1), tile = (bid>>1)&127 -> CU c holds
// blocks {c, c+256} = batches {p, p+2} at the same tile: per-CU work
// ~ (nkt_p + nkt_{p+2}), not 2*nkt_b (R14's b=bid&3 gave both blocks the
// SAME batch: (c+256)&3 == c&3 — pairing never happened).
// Wave = 16q x 32v, m89-verified geometry; row stride 40 ushorts.
// ---------------------------------------------------------------------------
__global__ __launch_bounds__(256) void pv_mfma_kernel(
    const unsigned short* __restrict__ attnQ, const unsigned short* __restrict__ Vt,
    const int* __restrict__ valid_lens, float* __restrict__ out) {
  const int bid = blockIdx.x;
  const int b = (bid & 1) | ((bid >> 8) << 1);
  const int tile = (bid >> 1) & 127;
  const int q0 = (tile >> 4) << 6;  // 8 q-tiles of 64
  const int v0 = (tile & 15) << 5;  // 16 v-tiles of 32

  __shared__ __align__(16) unsigned short Als[64 * 40];  // [q][k], 5 KB
  __shared__ __align__(16) unsigned short Bls[32 * 40];  // [v][k], 2.5 KB

  const int t = threadIdx.x;
  const int w = t >> 6, l = t & 63;
  const int lm = l & 15;
  const int lk = (l >> 4) << 3;

  const f32x4 z = {0.f, 0.f, 0.f, 0.f};
  f32x4 acc[2] = {z, z};

  const int vl = valid_lens[b];
  const int nkt = (vl + 31) >> 5;

  const int sq = t >> 2, seg = t & 3;
  const unsigned short* arow = attnQ + ((size_t)(b * NQ + q0 + sq)) * NK;
  unsigned short* alds = &Als[sq * 40 + (seg << 3)];
  const unsigned short* brow = Vt + ((size_t)(b * NK + v0 + (t >> 2))) * NK;
  unsigned short* blds = &Bls[(t >> 2) * 40 + (seg << 3)];

  for (int kt = 0; kt < nkt; ++kt) {
    const int k0 = kt << 5;
    *reinterpret_cast<bf16x8*>(alds) =
        *reinterpret_cast<const bf16x8*>(arow + k0 + (seg << 3));
    if (t < 128)
      *reinterpret_cast<bf16x8*>(blds) =
          *reinterpret_cast<const bf16x8*>(brow + k0 + (seg << 3));
    __syncthreads();

    const bf16x8 af = *reinterpret_cast<const bf16x8*>(
        &Als[((w << 4) + lm) * 40 + lk]);
#pragma unroll
    for (int nv = 0; nv < 2; ++nv) {
      const bf16x8 bfr = *reinterpret_cast<const bf16x8*>(
          &Bls[((nv << 4) + lm) * 40 + lk]);
      acc[nv] = __builtin_amdgcn_mfma_f32_16x16x32_bf16(af, bfr, acc[nv], 0, 0, 0);
    }
    __syncthreads();
  }

  // epilogue: D lane mapping col=lane&15, row=(lane>>4)*4+j  [m89-verified]
  const int rbase = (l >> 4) << 2;
#pragma unroll
  for (int nv = 0; nv < 2; ++nv) {
    const int qg = q0 + (w << 4) + rbase;
    const int vg = v0 + (nv << 4) + lm;
#pragma unroll
    for (int j = 0; j < 4; ++j)
      out[((size_t)(b * NQ + qg + j)) * DV + vg] = acc[nv][j];
  }
}

extern "C" void kernel_launch(void* const* d_in, const int* in_sizes, int n_in,
                              void* d_out, int out_size, void* d_ws, size_t ws_size,
                              hipStream_t stream) {
  (void)in_sizes; (void)n_in; (void)out_size; (void)ws_size;
  const float* queries = (const float*)d_in[0];
  const float* keys    = (const float*)d_in[1];
  const float* values  = (const float*)d_in[2];
  const float* Wq      = (const float*)d_in[3];
  const float* Wk      = (const float*)d_in[4];
  const float* Wv      = (const float*)d_in[5];
  const int*   vlens   = (const int*)d_in[6];
  float* out = (float*)d_out;
  float* ws = (float*)d_ws;

  // ws floats (NON-OVERLAPPING):
  //   eq    [0,        262144)
  //   ekT4  [262144,   524288)
  //   attnQ [524288,  1048576)  (1,048,576 ushort)
  //   Vt    [1048576, 1572864)  (1,048,576 ushort)
  float* eq   = ws;
  float* ekT4 = ws + 262144;
  unsigned short* attnQ = (unsigned short*)(ws + 524288);
  unsigned short* Vt    = (unsigned short*)(ws + 1048576);

  proj_mfma_vt_kernel<<<512, 256, 0, stream>>>(queries, keys, Wq, Wk, values,
                                               vlens, eq, ekT4, Vt);
  scores_softmax_kernel<<<512, 1024, 0, stream>>>(eq, ekT4, Wv, vlens, attnQ);
  pv_mfma_kernel<<<512, 256, 0, stream>>>(attnQ, Vt, vlens, out);
}

// Round 17
// 40.105 us; speedup vs baseline: 1.2551x; 1.1189x over previous
//
#include <hip/hip_runtime.h>

#ifndef __has_builtin
#define __has_builtin(x) 0
#endif

#if __has_builtin(__builtin_amdgcn_exp2f)
#define EXP2F(x) __builtin_amdgcn_exp2f(x)
#else
#define EXP2F(x) exp2f(x)
#endif
#if __has_builtin(__builtin_amdgcn_rcpf)
#define RCPF(x) __builtin_amdgcn_rcpf(x)
#else
#define RCPF(x) (1.0f / (x))
#endif

static constexpr int NB = 4, NQ = 512, NK = 512, DD = 512, HH = 128, DV = 512;
static constexpr float MASKV = -1e6f;
static constexpr float C2LOG2E = 2.885390081777926814f;  // 2*log2(e)

typedef __attribute__((ext_vector_type(8))) short bf16x8;
typedef __attribute__((ext_vector_type(4))) float f32x4;

__device__ __forceinline__ unsigned short f2bf(float x) {  // RNE f32->bf16
  unsigned int u = __float_as_uint(x);
  u += 0x7FFFu + ((u >> 16) & 1u);
  return (unsigned short)(u >> 16);
}
__device__ __forceinline__ float bf2f(unsigned short h) {
  return __uint_as_float(((unsigned int)h) << 16);
}
// split x = hi + lo (lo exact residual, then rounded): |x-hi-lo| <= 2^-18|x|
__device__ __forceinline__ void split2(float x, unsigned short& hi, unsigned short& lo) {
  hi = f2bf(x);
  lo = f2bf(x - bf2f(hi));
}

// ---------------------------------------------------------------------------
// K1: 512 blocks.  (R12-proven, FROZEN)
//  bid 0..255  : projection via split-bf16 MFMA, tile 16 rows x 128 h, full K.
//  bid 256..511: V transpose -> Vt[b][v][k] bf16.
// ---------------------------------------------------------------------------
__global__ __launch_bounds__(256) void proj_mfma_vt_kernel(
    const float* __restrict__ queries, const float* __restrict__ keys,
    const float* __restrict__ Wq, const float* __restrict__ Wk,
    const float* __restrict__ values, const int* __restrict__ valid_lens,
    float* __restrict__ eq, float* __restrict__ ekT4,
    unsigned short* __restrict__ Vt) {
  __shared__ __align__(16) unsigned short smem_us[20736];  // 41.5 KB
  const int bid = blockIdx.x;
  const int t = threadIdx.x;

  if (bid < 256) {
    const int row0 = bid << 4;
    const bool isK = row0 >= 2048;
    int b = 0, kloc = 0;
    const float* inb;
    const float* W;
    if (isK) {
      const int local = row0 - 2048;
      b = local >> 9;
      kloc = local & 511;
      if (kloc >= valid_lens[b]) return;  // fully-masked tile, never read
      inb = keys + (size_t)local * DD;
      W = Wk;
    } else {
      inb = queries + (size_t)row0 * DD;
      W = Wq;
    }

    unsigned short* Ah = smem_us;          // [16][72]
    unsigned short* Al = smem_us + 1152;   // [16][72]
    unsigned short* Wh = smem_us + 2304;   // [128][72] ([h][k])
    unsigned short* Wl = smem_us + 11520;  // [128][72]

    const int w = t >> 6, l = t & 63;
    const int lm = l & 15;
    const int lk8 = (l >> 4) << 3;

    const f32x4 z = {0.f, 0.f, 0.f, 0.f};
    f32x4 acc[2] = {z, z};  // col tiles h = 32w+0..15, 32w+16..31

    const int ar = t >> 4, ac4 = (t & 15) << 2;        // A staging: row, k4
    const int wh = t & 127, wkg = (t >> 7) << 5;       // W staging: h, k-group

    for (int kt = 0; kt < 8; ++kt) {
      const int k0 = kt << 6;
      {  // stage A: 16 rows x 64 k, split hi/lo, pack k-pairs into u32
        const float4 v = *reinterpret_cast<const float4*>(inb + (size_t)ar * DD + k0 + ac4);
        unsigned short h0, h1, h2, h3, l0, l1, l2, l3;
        split2(v.x, h0, l0); split2(v.y, h1, l1);
        split2(v.z, h2, l2); split2(v.w, h3, l3);
        uint2 ph = make_uint2((unsigned int)h0 | ((unsigned int)h1 << 16),
                              (unsigned int)h2 | ((unsigned int)h3 << 16));
        uint2 pl = make_uint2((unsigned int)l0 | ((unsigned int)l1 << 16),
                              (unsigned int)l2 | ((unsigned int)l3 << 16));
        *reinterpret_cast<uint2*>(Ah + ar * 72 + ac4) = ph;
        *reinterpret_cast<uint2*>(Al + ar * 72 + ac4) = pl;
      }
      {  // stage W transposed: [h][k], 32 k per thread (coalesced b32 loads)
        unsigned int hw[16], lw[16];
#pragma unroll
        for (int i = 0; i < 16; ++i) {
          const float w0 = W[(size_t)(k0 + wkg + 2 * i) * HH + wh];
          const float w1 = W[(size_t)(k0 + wkg + 2 * i + 1) * HH + wh];
          unsigned short a0, a1, b0, b1;
          split2(w0, a0, b0); split2(w1, a1, b1);
          hw[i] = (unsigned int)a0 | ((unsigned int)a1 << 16);
          lw[i] = (unsigned int)b0 | ((unsigned int)b1 << 16);
        }
        unsigned int* dh = reinterpret_cast<unsigned int*>(Wh + wh * 72 + wkg);
        unsigned int* dl = reinterpret_cast<unsigned int*>(Wl + wh * 72 + wkg);
#pragma unroll
        for (int i = 0; i < 4; ++i) {
          *reinterpret_cast<uint4*>(dh + 4 * i) =
              make_uint4(hw[4 * i], hw[4 * i + 1], hw[4 * i + 2], hw[4 * i + 3]);
          *reinterpret_cast<uint4*>(dl + 4 * i) =
              make_uint4(lw[4 * i], lw[4 * i + 1], lw[4 * i + 2], lw[4 * i + 3]);
        }
      }
      __syncthreads();

#pragma unroll
      for (int kh = 0; kh < 2; ++kh) {  // k halves 0..31 / 32..63
        const int ko = lk8 + (kh << 5);
        const bf16x8 ah = *reinterpret_cast<const bf16x8*>(Ah + lm * 72 + ko);
        const bf16x8 al = *reinterpret_cast<const bf16x8*>(Al + lm * 72 + ko);
#pragma unroll
        for (int c = 0; c < 2; ++c) {
          const int hrow = (w << 5) + (c << 4) + lm;
          const bf16x8 bh = *reinterpret_cast<const bf16x8*>(Wh + hrow * 72 + ko);
          const bf16x8 bl = *reinterpret_cast<const bf16x8*>(Wl + hrow * 72 + ko);
          acc[c] = __builtin_amdgcn_mfma_f32_16x16x32_bf16(ah, bh, acc[c], 0, 0, 0);
          acc[c] = __builtin_amdgcn_mfma_f32_16x16x32_bf16(al, bh, acc[c], 0, 0, 0);
          acc[c] = __builtin_amdgcn_mfma_f32_16x16x32_bf16(ah, bl, acc[c], 0, 0, 0);
        }
      }
      __syncthreads();
    }

    // epilogue: D mapping col=lane&15, row=(lane>>4)*4+j  [m89-verified]
    const int rb = (l >> 4) << 2;
    if (!isK) {
#pragma unroll
      for (int c = 0; c < 2; ++c) {
        const int h = (w << 5) + (c << 4) + lm;
#pragma unroll
        for (int j = 0; j < 4; ++j)
          eq[(size_t)(row0 + rb + j) * HH + h] = EXP2F(acc[c][j] * C2LOG2E);
      }
    } else {
      float* tile = reinterpret_cast<float*>(smem_us);  // [16][132] f32
#pragma unroll
      for (int c = 0; c < 2; ++c) {
        const int h = (w << 5) + (c << 4) + lm;
#pragma unroll
        for (int j = 0; j < 4; ++j)
          tile[(rb + j) * 132 + h] = EXP2F(acc[c][j] * C2LOG2E);
      }
      __syncthreads();
#pragma unroll
      for (int i = 0; i < 2; ++i) {
        const int idx = t + (i << 8);
        const int k = idx & 15, h4 = idx >> 4;  // h4 0..31
        const float4 v = *reinterpret_cast<const float4*>(tile + k * 132 + (h4 << 2));
        *reinterpret_cast<float4*>(
            ekT4 + ((((size_t)b * 32 + h4) << 9) + kloc + k) * 4) = v;
      }
    }
  } else {
    // V transpose (R10-proven)
    unsigned short (*tl)[72] = reinterpret_cast<unsigned short (*)[72]>(smem_us);
    const int vb = bid - 256;
    const int b = vb >> 6;
    const int tile = vb & 63;
    const int k0 = (tile >> 3) << 6;
    const int v0 = (tile & 7) << 6;
    const int kr = t >> 4, c4 = (t & 15) << 2;
#pragma unroll
    for (int pp = 0; pp < 4; ++pp) {
      const int k = kr + (pp << 4);
      const float4 v = *reinterpret_cast<const float4*>(
          values + ((size_t)(b * NK + k0 + k)) * DV + v0 + c4);
      tl[k][c4 + 0] = f2bf(v.x); tl[k][c4 + 1] = f2bf(v.y);
      tl[k][c4 + 2] = f2bf(v.z); tl[k][c4 + 3] = f2bf(v.w);
    }
    __syncthreads();
    const int vr = t >> 2, seg = t & 3;
    unsigned int pk[8];
#pragma unroll
    for (int i = 0; i < 8; ++i) {
      const int kc = (seg << 4) + (i << 1);
      pk[i] = (unsigned int)tl[kc][vr] | ((unsigned int)tl[kc + 1][vr] << 16);
    }
    unsigned short* dst = Vt + ((size_t)(b * NK + v0 + vr)) * NK + k0 + (seg << 4);
    *reinterpret_cast<uint4*>(dst) = make_uint4(pk[0], pk[1], pk[2], pk[3]);
    *reinterpret_cast<uint4*>(dst + 8) = make_uint4(pk[4], pk[5], pk[6], pk[7]);
  }
}

// ---------------------------------------------------------------------------
// K2: scores + masked softmax (R13-proven, FROZEN). 512 blocks x 1024 thr,
// q-tile 4, h-split x2; b = bid>>7 pairs batches {0,2}/{1,3} per CU.
// Paired-rcp inner loop. Output attnQ[b][q][k] bf16.
// ---------------------------------------------------------------------------
__global__ __launch_bounds__(1024) void scores_softmax_kernel(
    const float* __restrict__ eq, const float* __restrict__ ekT4,
    const float* __restrict__ Wv, const int* __restrict__ valid_lens,
    unsigned short* __restrict__ attnQ) {
  const int b = blockIdx.x >> 7;
  const int q0 = (blockIdx.x & 127) << 2;
  const int t = threadIdx.x;
  const int kk = t & 511, hh = t >> 9;

  __shared__ __align__(16) float qs[4][HH];
  __shared__ __align__(16) float wv[HH];
  __shared__ __align__(16) float scp[2][4][NK];  // 16 KB partials

  if (t < 512) {
    qs[t >> 7][t & 127] = eq[((size_t)(b * NQ + q0 + (t >> 7))) * HH + (t & 127)];
  } else if (t < 640) {
    wv[t - 512] = Wv[t - 512];
  }
  __syncthreads();

  const int vl = valid_lens[b];
  float s0 = 0.f, s1 = 0.f, s2 = 0.f, s3 = 0.f;

  if (kk < vl) {
    const float* ekb4 = ekT4 + (((size_t)(b * 32 + hh * 16) << 9) + kk) * 4;
#pragma unroll 8
    for (int i = 0; i < 16; ++i) {
      const float4 e4 = *reinterpret_cast<const float4*>(ekb4 + ((size_t)i << 11));
      const int h = (hh * 16 + i) << 2;
      const float4 w4 = *reinterpret_cast<const float4*>(&wv[h]);
      const float4 qa = *reinterpret_cast<const float4*>(&qs[0][h]);
      const float4 qb = *reinterpret_cast<const float4*>(&qs[1][h]);
      const float4 qc = *reinterpret_cast<const float4*>(&qs[2][h]);
      const float4 qd = *reinterpret_cast<const float4*>(&qs[3][h]);
      float u, v, num, r;
      // q-row 0: pairs (x,y), (z,w)
      u = fmaf(qa.x, e4.x, 1.f); v = fmaf(qa.y, e4.y, 1.f);
      num = fmaf(w4.x, v, w4.y * u); r = RCPF(u * v); s0 = fmaf(num, r, s0);
      u = fmaf(qa.z, e4.z, 1.f); v = fmaf(qa.w, e4.w, 1.f);
      num = fmaf(w4.z, v, w4.w * u); r = RCPF(u * v); s0 = fmaf(num, r, s0);
      // q-row 1
      u = fmaf(qb.x, e4.x, 1.f); v = fmaf(qb.y, e4.y, 1.f);
      num = fmaf(w4.x, v, w4.y * u); r = RCPF(u * v); s1 = fmaf(num, r, s1);
      u = fmaf(qb.z, e4.z, 1.f); v = fmaf(qb.w, e4.w, 1.f);
      num = fmaf(w4.z, v, w4.w * u); r = RCPF(u * v); s1 = fmaf(num, r, s1);
      // q-row 2
      u = fmaf(qc.x, e4.x, 1.f); v = fmaf(qc.y, e4.y, 1.f);
      num = fmaf(w4.x, v, w4.y * u); r = RCPF(u * v); s2 = fmaf(num, r, s2);
      u = fmaf(qc.z, e4.z, 1.f); v = fmaf(qc.w, e4.w, 1.f);
      num = fmaf(w4.z, v, w4.w * u); r = RCPF(u * v); s2 = fmaf(num, r, s2);
      // q-row 3
      u = fmaf(qd.x, e4.x, 1.f); v = fmaf(qd.y, e4.y, 1.f);
      num = fmaf(w4.x, v, w4.y * u); r = RCPF(u * v); s3 = fmaf(num, r, s3);
      u = fmaf(qd.z, e4.z, 1.f); v = fmaf(qd.w, e4.w, 1.f);
      num = fmaf(w4.z, v, w4.w * u); r = RCPF(u * v); s3 = fmaf(num, r, s3);
    }
  }
  scp[hh][0][kk] = s0;
  scp[hh][1][kk] = s1;
  scp[hh][2][kk] = s2;
  scp[hh][3][kk] = s3;
  __syncthreads();

  if (t < 256) {
    const int w = t >> 6, l = t & 63;
    float v[8];
#pragma unroll
    for (int j = 0; j < 8; ++j) {
      const int k = l + (j << 6);
      const float sv = scp[0][w][k] + scp[1][w][k];
      v[j] = (k < vl) ? (-2.f * sv) : MASKV;
    }
    float m = v[0];
#pragma unroll
    for (int j = 1; j < 8; ++j) m = fmaxf(m, v[j]);
#pragma unroll
    for (int off = 32; off > 0; off >>= 1) m = fmaxf(m, __shfl_xor(m, off, 64));
    float p[8], sum = 0.f;
#pragma unroll
    for (int j = 0; j < 8; ++j) {
      p[j] = __expf(v[j] - m);  // masked: underflows to exactly 0
      sum += p[j];
    }
#pragma unroll
    for (int off = 32; off > 0; off >>= 1) sum += __shfl_xor(sum, off, 64);
    const float inv = RCPF(sum);
#pragma unroll
    for (int j = 0; j < 8; ++j) scp[0][w][l + (j << 6)] = p[j] * inv;
  }
  __syncthreads();

  if (t < 512) {
#pragma unroll
    for (int j = 0; j < 4; ++j)
      attnQ[((size_t)(b * NQ + q0 + j)) * NK + t] = f2bf(scp[0][j][t]);
  }
}

// ---------------------------------------------------------------------------
// K3: PV via MFMA bf16, 64q x 64v @ 256 blocks (R13 shape RESTORED).
// R16 (fixed): 512 threads (8 waves; wave = 16q x 32v, 4 MFMA/iter) +
// double-buffered T14 staging: issue next K-chunk's global loads -> MFMA on
// current buffer -> write regs to other buffer -> ONE barrier per iter.
// K-chunk 64 (nkt <= 8). Row stride 72 ushorts (proven). m89 D-mapping.
// ---------------------------------------------------------------------------
__global__ __launch_bounds__(512) void pv_mfma_kernel(
    const unsigned short* __restrict__ attnQ, const unsigned short* __restrict__ Vt,
    const int* __restrict__ valid_lens, float* __restrict__ out) {
  const int bid = blockIdx.x;
  const int b = bid & 3;            // adjacent blocks -> different batches
  const int tile = bid >> 2;
  const int q0 = (tile >> 3) << 6;
  const int v0 = (tile & 7) << 6;

  __shared__ __align__(16) unsigned short Als[2][64 * 72];  // [q][k64]
  __shared__ __align__(16) unsigned short Bls[2][64 * 72];  // [v][k64]

  const int t = threadIdx.x;
  const int w = t >> 6, l = t & 63;
  const int lm = l & 15;
  const int lk = (l >> 4) << 3;     // 0,8,16,24
  const int wq = (w & 3) << 4;      // q-tile 0,16,32,48
  const int wv = (w >> 2) << 5;     // v-half 0,32

  const f32x4 z = {0.f, 0.f, 0.f, 0.f};
  f32x4 acc[2] = {z, z};

  const int vl = valid_lens[b];
  const int nkt = (vl + 63) >> 6;   // K-chunks of 64

  // staging role: t<256 -> A (attnQ), t>=256 -> B (Vt). row sr, segs {seg, seg+4}.
  const bool isA = t < 256;
  const int sr = (t & 255) >> 2, seg = t & 3;
  const unsigned short* src = isA
      ? attnQ + ((size_t)(b * NQ + q0 + sr)) * NK + (seg << 3)
      : Vt + ((size_t)(b * NK + v0 + sr)) * NK + (seg << 3);
  unsigned short* dst0 = (isA ? Als[0] : Bls[0]) + sr * 72 + (seg << 3);
  unsigned short* dst1 = (isA ? Als[1] : Bls[1]) + sr * 72 + (seg << 3);

  // prologue: stage chunk 0 into buffer 0
  {
    const bf16x8 r0 = *reinterpret_cast<const bf16x8*>(src);
    const bf16x8 r1 = *reinterpret_cast<const bf16x8*>(src + 32);
    *reinterpret_cast<bf16x8*>(dst0) = r0;
    *reinterpret_cast<bf16x8*>(dst0 + 32) = r1;
  }
  __syncthreads();

  for (int kt = 0; kt < nkt; ++kt) {
    const int cur = kt & 1;
    const bool more = (kt + 1) < nkt;
    bf16x8 r0, r1;
    if (more) {  // issue next chunk's loads (use deferred until after MFMA)
      const unsigned short* s = src + (((size_t)(kt + 1)) << 6);
      r0 = *reinterpret_cast<const bf16x8*>(s);
      r1 = *reinterpret_cast<const bf16x8*>(s + 32);
    }

    const unsigned short* Ab = cur ? Als[1] : Als[0];
    const unsigned short* Bb = cur ? Bls[1] : Bls[0];
#pragma unroll
    for (int kh = 0; kh < 2; ++kh) {
      const int ko = lk + (kh << 5);
      const bf16x8 af = *reinterpret_cast<const bf16x8*>(Ab + (wq + lm) * 72 + ko);
#pragma unroll
      for (int nv = 0; nv < 2; ++nv) {
        const bf16x8 bfr = *reinterpret_cast<const bf16x8*>(
            Bb + (wv + (nv << 4) + lm) * 72 + ko);
        acc[nv] = __builtin_amdgcn_mfma_f32_16x16x32_bf16(af, bfr, acc[nv], 0, 0, 0);
      }
    }

    if (more) {  // write prefetched regs to the other buffer (read last iter)
      unsigned short* d = cur ? dst0 : dst1;
      *reinterpret_cast<bf16x8*>(d) = r0;
      *reinterpret_cast<bf16x8*>(d + 32) = r1;
    }
    __syncthreads();
  }

  // epilogue: D lane mapping col=lane&15, row=(lane>>4)*4+j  [m89-verified]
  const int rbase = (l >> 4) << 2;
#pragma unroll
  for (int nv = 0; nv < 2; ++nv) {
    const int qg = q0 + wq + rbase;
    const int vg = v0 + wv + (nv << 4) + lm;
#pragma unroll
    for (int j = 0; j < 4; ++j)
      out[((size_t)(b * NQ + qg + j)) * DV + vg] = acc[nv][j];
  }
}

extern "C" void kernel_launch(void* const* d_in, const int* in_sizes, int n_in,
                              void* d_out, int out_size, void* d_ws, size_t ws_size,
                              hipStream_t stream) {
  (void)in_sizes; (void)n_in; (void)out_size; (void)ws_size;
  const float* queries = (const float*)d_in[0];
  const float* keys    = (const float*)d_in[1];
  const float* values  = (const float*)d_in[2];
  const float* Wq      = (const float*)d_in[3];
  const float* Wk      = (const float*)d_in[4];
  const float* Wv      = (const float*)d_in[5];
  const int*   vlens   = (const int*)d_in[6];
  float* out = (float*)d_out;
  float* ws = (float*)d_ws;

  // ws floats (NON-OVERLAPPING):
  //   eq    [0,        262144)
  //   ekT4  [262144,   524288)
  //   attnQ [524288,  1048576)  (1,048,576 ushort)
  //   Vt    [1048576, 1572864)  (1,048,576 ushort)
  float* eq   = ws;
  float* ekT4 = ws + 262144;
  unsigned short* attnQ = (unsigned short*)(ws + 524288);
  unsigned short* Vt    = (unsigned short*)(ws + 1048576);

  proj_mfma_vt_kernel<<<512, 256, 0, stream>>>(queries, keys, Wq, Wk, values,
                                               vlens, eq, ekT4, Vt);
  scores_softmax_kernel<<<512, 1024, 0, stream>>>(eq, ekT4, Wv, vlens, attnQ);
  pv_mfma_kernel<<<256, 512, 0, stream>>>(attnQ, Vt, vlens, out);
}

// Round 18
// 39.868 us; speedup vs baseline: 1.2625x; 1.0059x over previous
//
#include <hip/hip_runtime.h>

#ifndef __has_builtin
#define __has_builtin(x) 0
#endif

#if __has_builtin(__builtin_amdgcn_exp2f)
#define EXP2F(x) __builtin_amdgcn_exp2f(x)
#else
#define EXP2F(x) exp2f(x)
#endif
#if __has_builtin(__builtin_amdgcn_rcpf)
#define RCPF(x) __builtin_amdgcn_rcpf(x)
#else
#define RCPF(x) (1.0f / (x))
#endif

static constexpr int NB = 4, NQ = 512, NK = 512, DD = 512, HH = 128, DV = 512;
static constexpr float MASKV = -1e6f;
static constexpr float C2LOG2E = 2.885390081777926814f;  // 2*log2(e)

typedef __attribute__((ext_vector_type(8))) short bf16x8;
typedef __attribute__((ext_vector_type(4))) float f32x4;

__device__ __forceinline__ unsigned short f2bf(float x) {  // RNE f32->bf16
  unsigned int u = __float_as_uint(x);
  u += 0x7FFFu + ((u >> 16) & 1u);
  return (unsigned short)(u >> 16);
}
__device__ __forceinline__ float bf2f(unsigned short h) {
  return __uint_as_float(((unsigned int)h) << 16);
}
// split x = hi + lo (lo exact residual, then rounded): |x-hi-lo| <= 2^-18|x|
__device__ __forceinline__ void split2(float x, unsigned short& hi, unsigned short& lo) {
  hi = f2bf(x);
  lo = f2bf(x - bf2f(hi));
}

// ---------------------------------------------------------------------------
// K1: 512 blocks.
//  bid 0..255  : projection via split-bf16 MFMA (R12-proven geometry).
//                CHANGE (R18): register-prefetch pipeline (R17-proven in pv):
//                {split+write regs->LDS; barrier; issue kt+1 loads->regs;
//                 MFMA; barrier} — global latency hides under MFMA phase.
//                Single LDS buffer (write phase is behind the post-MFMA
//                barrier). +36 VGPR prefetch state.
//  bid 256..511: V transpose -> Vt[b][v][k] bf16 (R10-proven, FROZEN).
// ---------------------------------------------------------------------------
__global__ __launch_bounds__(256) void proj_mfma_vt_kernel(
    const float* __restrict__ queries, const float* __restrict__ keys,
    const float* __restrict__ Wq, const float* __restrict__ Wk,
    const float* __restrict__ values, const int* __restrict__ valid_lens,
    float* __restrict__ eq, float* __restrict__ ekT4,
    unsigned short* __restrict__ Vt) {
  __shared__ __align__(16) unsigned short smem_us[20736];  // 41.5 KB
  const int bid = blockIdx.x;
  const int t = threadIdx.x;

  if (bid < 256) {
    const int row0 = bid << 4;
    const bool isK = row0 >= 2048;
    int b = 0, kloc = 0;
    const float* inb;
    const float* W;
    if (isK) {
      const int local = row0 - 2048;
      b = local >> 9;
      kloc = local & 511;
      if (kloc >= valid_lens[b]) return;  // fully-masked tile, never read
      inb = keys + (size_t)local * DD;
      W = Wk;
    } else {
      inb = queries + (size_t)row0 * DD;
      W = Wq;
    }

    unsigned short* Ah = smem_us;          // [16][72]
    unsigned short* Al = smem_us + 1152;   // [16][72]
    unsigned short* Wh = smem_us + 2304;   // [128][72] ([h][k])
    unsigned short* Wl = smem_us + 11520;  // [128][72]

    const int w = t >> 6, l = t & 63;
    const int lm = l & 15;
    const int lk8 = (l >> 4) << 3;

    const f32x4 z = {0.f, 0.f, 0.f, 0.f};
    f32x4 acc[2] = {z, z};  // col tiles h = 32w+0..15, 32w+16..31

    const int ar = t >> 4, ac4 = (t & 15) << 2;        // A staging: row, k4
    const int wh = t & 127, wkg = (t >> 7) << 5;       // W staging: h, k-group

    // prefetch kt=0 into registers
    float4 aV = *reinterpret_cast<const float4*>(inb + (size_t)ar * DD + ac4);
    float wr[32];
#pragma unroll
    for (int i = 0; i < 32; ++i)
      wr[i] = W[(size_t)(wkg + i) * HH + wh];

    for (int kt = 0; kt < 8; ++kt) {
      {  // split & write A from regs
        unsigned short h0, h1, h2, h3, l0, l1, l2, l3;
        split2(aV.x, h0, l0); split2(aV.y, h1, l1);
        split2(aV.z, h2, l2); split2(aV.w, h3, l3);
        uint2 ph = make_uint2((unsigned int)h0 | ((unsigned int)h1 << 16),
                              (unsigned int)h2 | ((unsigned int)h3 << 16));
        uint2 pl = make_uint2((unsigned int)l0 | ((unsigned int)l1 << 16),
                              (unsigned int)l2 | ((unsigned int)l3 << 16));
        *reinterpret_cast<uint2*>(Ah + ar * 72 + ac4) = ph;
        *reinterpret_cast<uint2*>(Al + ar * 72 + ac4) = pl;
      }
      {  // split & write W from regs
        unsigned int hw[16], lw[16];
#pragma unroll
        for (int i = 0; i < 16; ++i) {
          unsigned short a0, a1, b0, b1;
          split2(wr[2 * i], a0, b0); split2(wr[2 * i + 1], a1, b1);
          hw[i] = (unsigned int)a0 | ((unsigned int)a1 << 16);
          lw[i] = (unsigned int)b0 | ((unsigned int)b1 << 16);
        }
        unsigned int* dh = reinterpret_cast<unsigned int*>(Wh + wh * 72 + wkg);
        unsigned int* dl = reinterpret_cast<unsigned int*>(Wl + wh * 72 + wkg);
#pragma unroll
        for (int i = 0; i < 4; ++i) {
          *reinterpret_cast<uint4*>(dh + 4 * i) =
              make_uint4(hw[4 * i], hw[4 * i + 1], hw[4 * i + 2], hw[4 * i + 3]);
          *reinterpret_cast<uint4*>(dl + 4 * i) =
              make_uint4(lw[4 * i], lw[4 * i + 1], lw[4 * i + 2], lw[4 * i + 3]);
        }
      }
      __syncthreads();

      if (kt < 7) {  // issue kt+1's global loads; latency hides under MFMA
        const int k0n = (kt + 1) << 6;
        aV = *reinterpret_cast<const float4*>(inb + (size_t)ar * DD + k0n + ac4);
#pragma unroll
        for (int i = 0; i < 32; ++i)
          wr[i] = W[(size_t)(k0n + wkg + i) * HH + wh];
      }

#pragma unroll
      for (int kh = 0; kh < 2; ++kh) {  // k halves 0..31 / 32..63
        const int ko = lk8 + (kh << 5);
        const bf16x8 ah = *reinterpret_cast<const bf16x8*>(Ah + lm * 72 + ko);
        const bf16x8 al = *reinterpret_cast<const bf16x8*>(Al + lm * 72 + ko);
#pragma unroll
        for (int c = 0; c < 2; ++c) {
          const int hrow = (w << 5) + (c << 4) + lm;
          const bf16x8 bh = *reinterpret_cast<const bf16x8*>(Wh + hrow * 72 + ko);
          const bf16x8 bl = *reinterpret_cast<const bf16x8*>(Wl + hrow * 72 + ko);
          acc[c] = __builtin_amdgcn_mfma_f32_16x16x32_bf16(ah, bh, acc[c], 0, 0, 0);
          acc[c] = __builtin_amdgcn_mfma_f32_16x16x32_bf16(al, bh, acc[c], 0, 0, 0);
          acc[c] = __builtin_amdgcn_mfma_f32_16x16x32_bf16(ah, bl, acc[c], 0, 0, 0);
        }
      }
      __syncthreads();
    }

    // epilogue: D mapping col=lane&15, row=(lane>>4)*4+j  [m89-verified]
    const int rb = (l >> 4) << 2;
    if (!isK) {
#pragma unroll
      for (int c = 0; c < 2; ++c) {
        const int h = (w << 5) + (c << 4) + lm;
#pragma unroll
        for (int j = 0; j < 4; ++j)
          eq[(size_t)(row0 + rb + j) * HH + h] = EXP2F(acc[c][j] * C2LOG2E);
      }
    } else {
      float* tile = reinterpret_cast<float*>(smem_us);  // [16][132] f32
#pragma unroll
      for (int c = 0; c < 2; ++c) {
        const int h = (w << 5) + (c << 4) + lm;
#pragma unroll
        for (int j = 0; j < 4; ++j)
          tile[(rb + j) * 132 + h] = EXP2F(acc[c][j] * C2LOG2E);
      }
      __syncthreads();
#pragma unroll
      for (int i = 0; i < 2; ++i) {
        const int idx = t + (i << 8);
        const int k = idx & 15, h4 = idx >> 4;  // h4 0..31
        const float4 v = *reinterpret_cast<const float4*>(tile + k * 132 + (h4 << 2));
        *reinterpret_cast<float4*>(
            ekT4 + ((((size_t)b * 32 + h4) << 9) + kloc + k) * 4) = v;
      }
    }
  } else {
    // V transpose (R10-proven)
    unsigned short (*tl)[72] = reinterpret_cast<unsigned short (*)[72]>(smem_us);
    const int vb = bid - 256;
    const int b = vb >> 6;
    const int tile = vb & 63;
    const int k0 = (tile >> 3) << 6;
    const int v0 = (tile & 7) << 6;
    const int kr = t >> 4, c4 = (t & 15) << 2;
#pragma unroll
    for (int pp = 0; pp < 4; ++pp) {
      const int k = kr + (pp << 4);
      const float4 v = *reinterpret_cast<const float4*>(
          values + ((size_t)(b * NK + k0 + k)) * DV + v0 + c4);
      tl[k][c4 + 0] = f2bf(v.x); tl[k][c4 + 1] = f2bf(v.y);
      tl[k][c4 + 2] = f2bf(v.z); tl[k][c4 + 3] = f2bf(v.w);
    }
    __syncthreads();
    const int vr = t >> 2, seg = t & 3;
    unsigned int pk[8];
#pragma unroll
    for (int i = 0; i < 8; ++i) {
      const int kc = (seg << 4) + (i << 1);
      pk[i] = (unsigned int)tl[kc][vr] | ((unsigned int)tl[kc + 1][vr] << 16);
    }
    unsigned short* dst = Vt + ((size_t)(b * NK + v0 + vr)) * NK + k0 + (seg << 4);
    *reinterpret_cast<uint4*>(dst) = make_uint4(pk[0], pk[1], pk[2], pk[3]);
    *reinterpret_cast<uint4*>(dst + 8) = make_uint4(pk[4], pk[5], pk[6], pk[7]);
  }
}

// ---------------------------------------------------------------------------
// K2: scores + masked softmax (R13-proven, FROZEN). 512 blocks x 1024 thr,
// q-tile 4, h-split x2; b = bid>>7 pairs batches {0,2}/{1,3} per CU.
// Paired-rcp inner loop. Output attnQ[b][q][k] bf16.
// ---------------------------------------------------------------------------
__global__ __launch_bounds__(1024) void scores_softmax_kernel(
    const float* __restrict__ eq, const float* __restrict__ ekT4,
    const float* __restrict__ Wv, const int* __restrict__ valid_lens,
    unsigned short* __restrict__ attnQ) {
  const int b = blockIdx.x >> 7;
  const int q0 = (blockIdx.x & 127) << 2;
  const int t = threadIdx.x;
  const int kk = t & 511, hh = t >> 9;

  __shared__ __align__(16) float qs[4][HH];
  __shared__ __align__(16) float wv[HH];
  __shared__ __align__(16) float scp[2][4][NK];  // 16 KB partials

  if (t < 512) {
    qs[t >> 7][t & 127] = eq[((size_t)(b * NQ + q0 + (t >> 7))) * HH + (t & 127)];
  } else if (t < 640) {
    wv[t - 512] = Wv[t - 512];
  }
  __syncthreads();

  const int vl = valid_lens[b];
  float s0 = 0.f, s1 = 0.f, s2 = 0.f, s3 = 0.f;

  if (kk < vl) {
    const float* ekb4 = ekT4 + (((size_t)(b * 32 + hh * 16) << 9) + kk) * 4;
#pragma unroll 8
    for (int i = 0; i < 16; ++i) {
      const float4 e4 = *reinterpret_cast<const float4*>(ekb4 + ((size_t)i << 11));
      const int h = (hh * 16 + i) << 2;
      const float4 w4 = *reinterpret_cast<const float4*>(&wv[h]);
      const float4 qa = *reinterpret_cast<const float4*>(&qs[0][h]);
      const float4 qb = *reinterpret_cast<const float4*>(&qs[1][h]);
      const float4 qc = *reinterpret_cast<const float4*>(&qs[2][h]);
      const float4 qd = *reinterpret_cast<const float4*>(&qs[3][h]);
      float u, v, num, r;
      // q-row 0: pairs (x,y), (z,w)
      u = fmaf(qa.x, e4.x, 1.f); v = fmaf(qa.y, e4.y, 1.f);
      num = fmaf(w4.x, v, w4.y * u); r = RCPF(u * v); s0 = fmaf(num, r, s0);
      u = fmaf(qa.z, e4.z, 1.f); v = fmaf(qa.w, e4.w, 1.f);
      num = fmaf(w4.z, v, w4.w * u); r = RCPF(u * v); s0 = fmaf(num, r, s0);
      // q-row 1
      u = fmaf(qb.x, e4.x, 1.f); v = fmaf(qb.y, e4.y, 1.f);
      num = fmaf(w4.x, v, w4.y * u); r = RCPF(u * v); s1 = fmaf(num, r, s1);
      u = fmaf(qb.z, e4.z, 1.f); v = fmaf(qb.w, e4.w, 1.f);
      num = fmaf(w4.z, v, w4.w * u); r = RCPF(u * v); s1 = fmaf(num, r, s1);
      // q-row 2
      u = fmaf(qc.x, e4.x, 1.f); v = fmaf(qc.y, e4.y, 1.f);
      num = fmaf(w4.x, v, w4.y * u); r = RCPF(u * v); s2 = fmaf(num, r, s2);
      u = fmaf(qc.z, e4.z, 1.f); v = fmaf(qc.w, e4.w, 1.f);
      num = fmaf(w4.z, v, w4.w * u); r = RCPF(u * v); s2 = fmaf(num, r, s2);
      // q-row 3
      u = fmaf(qd.x, e4.x, 1.f); v = fmaf(qd.y, e4.y, 1.f);
      num = fmaf(w4.x, v, w4.y * u); r = RCPF(u * v); s3 = fmaf(num, r, s3);
      u = fmaf(qd.z, e4.z, 1.f); v = fmaf(qd.w, e4.w, 1.f);
      num = fmaf(w4.z, v, w4.w * u); r = RCPF(u * v); s3 = fmaf(num, r, s3);
    }
  }
  scp[hh][0][kk] = s0;
  scp[hh][1][kk] = s1;
  scp[hh][2][kk] = s2;
  scp[hh][3][kk] = s3;
  __syncthreads();

  if (t < 256) {
    const int w = t >> 6, l = t & 63;
    float v[8];
#pragma unroll
    for (int j = 0; j < 8; ++j) {
      const int k = l + (j << 6);
      const float sv = scp[0][w][k] + scp[1][w][k];
      v[j] = (k < vl) ? (-2.f * sv) : MASKV;
    }
    float m = v[0];
#pragma unroll
    for (int j = 1; j < 8; ++j) m = fmaxf(m, v[j]);
#pragma unroll
    for (int off = 32; off > 0; off >>= 1) m = fmaxf(m, __shfl_xor(m, off, 64));
    float p[8], sum = 0.f;
#pragma unroll
    for (int j = 0; j < 8; ++j) {
      p[j] = __expf(v[j] - m);  // masked: underflows to exactly 0
      sum += p[j];
    }
#pragma unroll
    for (int off = 32; off > 0; off >>= 1) sum += __shfl_xor(sum, off, 64);
    const float inv = RCPF(sum);
#pragma unroll
    for (int j = 0; j < 8; ++j) scp[0][w][l + (j << 6)] = p[j] * inv;
  }
  __syncthreads();

  if (t < 512) {
#pragma unroll
    for (int j = 0; j < 4; ++j)
      attnQ[((size_t)(b * NQ + q0 + j)) * NK + t] = f2bf(scp[0][j][t]);
  }
}

// ---------------------------------------------------------------------------
// K3: PV via MFMA bf16 (R17-proven, FROZEN). 64q x 64v @ 256 blocks,
// 512 threads (8 waves; wave = 16q x 32v), double-buffered T14 staging.
// ---------------------------------------------------------------------------
__global__ __launch_bounds__(512) void pv_mfma_kernel(
    const unsigned short* __restrict__ attnQ, const unsigned short* __restrict__ Vt,
    const int* __restrict__ valid_lens, float* __restrict__ out) {
  const int bid = blockIdx.x;
  const int b = bid & 3;            // adjacent blocks -> different batches
  const int tile = bid >> 2;
  const int q0 = (tile >> 3) << 6;
  const int v0 = (tile & 7) << 6;

  __shared__ __align__(16) unsigned short Als[2][64 * 72];  // [q][k64]
  __shared__ __align__(16) unsigned short Bls[2][64 * 72];  // [v][k64]

  const int t = threadIdx.x;
  const int w = t >> 6, l = t & 63;
  const int lm = l & 15;
  const int lk = (l >> 4) << 3;     // 0,8,16,24
  const int wq = (w & 3) << 4;      // q-tile 0,16,32,48
  const int wv = (w >> 2) << 5;     // v-half 0,32

  const f32x4 z = {0.f, 0.f, 0.f, 0.f};
  f32x4 acc[2] = {z, z};

  const int vl = valid_lens[b];
  const int nkt = (vl + 63) >> 6;   // K-chunks of 64

  // staging role: t<256 -> A (attnQ), t>=256 -> B (Vt). row sr, segs {seg, seg+4}.
  const bool isA = t < 256;
  const int sr = (t & 255) >> 2, seg = t & 3;
  const unsigned short* src = isA
      ? attnQ + ((size_t)(b * NQ + q0 + sr)) * NK + (seg << 3)
      : Vt + ((size_t)(b * NK + v0 + sr)) * NK + (seg << 3);
  unsigned short* dst0 = (isA ? Als[0] : Bls[0]) + sr * 72 + (seg << 3);
  unsigned short* dst1 = (isA ? Als[1] : Bls[1]) + sr * 72 + (seg << 3);

  // prologue: stage chunk 0 into buffer 0
  {
    const bf16x8 r0 = *reinterpret_cast<const bf16x8*>(src);
    const bf16x8 r1 = *reinterpret_cast<const bf16x8*>(src + 32);
    *reinterpret_cast<bf16x8*>(dst0) = r0;
    *reinterpret_cast<bf16x8*>(dst0 + 32) = r1;
  }
  __syncthreads();

  for (int kt = 0; kt < nkt; ++kt) {
    const int cur = kt & 1;
    const bool more = (kt + 1) < nkt;
    bf16x8 r0, r1;
    if (more) {  // issue next chunk's loads (use deferred until after MFMA)
      const unsigned short* s = src + (((size_t)(kt + 1)) << 6);
      r0 = *reinterpret_cast<const bf16x8*>(s);
      r1 = *reinterpret_cast<const bf16x8*>(s + 32);
    }

    const unsigned short* Ab = cur ? Als[1] : Als[0];
    const unsigned short* Bb = cur ? Bls[1] : Bls[0];
#pragma unroll
    for (int kh = 0; kh < 2; ++kh) {
      const int ko = lk + (kh << 5);
      const bf16x8 af = *reinterpret_cast<const bf16x8*>(Ab + (wq + lm) * 72 + ko);
#pragma unroll
      for (int nv = 0; nv < 2; ++nv) {
        const bf16x8 bfr = *reinterpret_cast<const bf16x8*>(
            Bb + (wv + (nv << 4) + lm) * 72 + ko);
        acc[nv] = __builtin_amdgcn_mfma_f32_16x16x32_bf16(af, bfr, acc[nv], 0, 0, 0);
      }
    }

    if (more) {  // write prefetched regs to the other buffer (read last iter)
      unsigned short* d = cur ? dst0 : dst1;
      *reinterpret_cast<bf16x8*>(d) = r0;
      *reinterpret_cast<bf16x8*>(d + 32) = r1;
    }
    __syncthreads();
  }

  // epilogue: D lane mapping col=lane&15, row=(lane>>4)*4+j  [m89-verified]
  const int rbase = (l >> 4) << 2;
#pragma unroll
  for (int nv = 0; nv < 2; ++nv) {
    const int qg = q0 + wq + rbase;
    const int vg = v0 + wv + (nv << 4) + lm;
#pragma unroll
    for (int j = 0; j < 4; ++j)
      out[((size_t)(b * NQ + qg + j)) * DV + vg] = acc[nv][j];
  }
}

extern "C" void kernel_launch(void* const* d_in, const int* in_sizes, int n_in,
                              void* d_out, int out_size, void* d_ws, size_t ws_size,
                              hipStream_t stream) {
  (void)in_sizes; (void)n_in; (void)out_size; (void)ws_size;
  const float* queries = (const float*)d_in[0];
  const float* keys    = (const float*)d_in[1];
  const float* values  = (const float*)d_in[2];
  const float* Wq      = (const float*)d_in[3];
  const float* Wk      = (const float*)d_in[4];
  const float* Wv      = (const float*)d_in[5];
  const int*   vlens   = (const int*)d_in[6];
  float* out = (float*)d_out;
  float* ws = (float*)d_ws;

  // ws floats (NON-OVERLAPPING):
  //   eq    [0,        262144)
  //   ekT4  [262144,   524288)
  //   attnQ [524288,  1048576)  (1,048,576 ushort)
  //   Vt    [1048576, 1572864)  (1,048,576 ushort)
  float* eq   = ws;
  float* ekT4 = ws + 262144;
  unsigned short* attnQ = (unsigned short*)(ws + 524288);
  unsigned short* Vt    = (unsigned short*)(ws + 1048576);

  proj_mfma_vt_kernel<<<512, 256, 0, stream>>>(queries, keys, Wq, Wk, values,
                                               vlens, eq, ekT4, Vt);
  scores_softmax_kernel<<<512, 1024, 0, stream>>>(eq, ekT4, Wv, vlens, attnQ);
  pv_mfma_kernel<<<256, 512, 0, stream>>>(attnQ, Vt, vlens, out);
}